// Round 7
// baseline (1580.733 us; speedup 1.0000x reference)
//
#include <hip/hip_runtime.h>
#include <hip/hip_bf16.h>

#define NN 50000
#define NE 800000
#define HD 128
#define EPSV 1e-5f
#define TE 64
#define BLK 256
#define SROW 68          // fp32 LDS row stride for input/final kernels
#define ASTR 336         // bufA row stride bytes: 168 bf16
#define BSTR 272         // bufB row stride bytes: 136 bf16

typedef unsigned short u16;
typedef __attribute__((ext_vector_type(8))) short bf16x8;
typedef __attribute__((ext_vector_type(4))) float f32x4;
#define MFMA16 __builtin_amdgcn_mfma_f32_16x16x32_bf16

__device__ __forceinline__ float sigm(float x){ return 1.0f/(1.0f+__expf(-x)); }
__device__ __forceinline__ void atomAddF(float* p, float v){ unsafeAtomicAdd(p, v); }
__device__ __forceinline__ unsigned bfr(float x){           // f32 -> bf16 bits (RNE)
    unsigned u = __float_as_uint(x);
    return (u + 0x7FFFu + ((u>>16)&1u)) >> 16;
}
__device__ __forceinline__ float bf2f(unsigned u){ return __uint_as_float(u<<16); }

// ---------------- small utility kernels ----------------
__global__ void zero_i_k(int* __restrict__ p, int n){
    int i = blockIdx.x*blockDim.x + threadIdx.x;
    if (i < n) p[i] = 0;
}
__global__ void zero_bn_k(float* __restrict__ bn){ bn[threadIdx.x] = 0.0f; }

__global__ void count_k(const int* __restrict__ dst, int* __restrict__ cnt){
    int e = blockIdx.x*blockDim.x + threadIdx.x;
    if (e < NE) atomicAdd(&cnt[dst[e]], 1);
}
__global__ void rdenom_k(const int* __restrict__ cnt, float* __restrict__ rd){
    int i = blockIdx.x*blockDim.x + threadIdx.x;
    if (i < NN) rd[i] = 1.0f / fmaxf((float)cnt[i], 1.0f);
}

// single-block exclusive scan over NN ints -> CSR offsets; off[NN] = NE
__global__ __launch_bounds__(1024) void scan_k(const int* __restrict__ cnt, int* __restrict__ off){
    __shared__ int s[1024];
    __shared__ int carryS;
    const int tid = threadIdx.x;
    if (tid == 0) carryS = 0;
    __syncthreads();
    const int NCH = (NN + 1023) / 1024;
    for (int ch = 0; ch < NCH; ++ch){
        const int i = ch*1024 + tid;
        const int v = (i < NN) ? cnt[i] : 0;
        s[tid] = v;
        __syncthreads();
        #pragma unroll
        for (int ofs = 1; ofs < 1024; ofs <<= 1){
            int t = (tid >= ofs) ? s[tid-ofs] : 0;
            __syncthreads();
            s[tid] += t;
            __syncthreads();
        }
        const int carry = carryS;
        if (i < NN) off[i] = carry + s[tid] - v;
        __syncthreads();
        if (tid == 1023) carryS = carry + s[1023];
        __syncthreads();
    }
    if (tid == 0) off[NN] = NE;
}

__global__ void fill_k(const int* __restrict__ dst, const int* __restrict__ off,
                       int* __restrict__ fill, int* __restrict__ eidx){
    int e = blockIdx.x*blockDim.x + threadIdx.x;
    if (e < NE){
        int d = dst[e];
        int pos = atomicAdd(&fill[d], 1);
        eidx[off[d] + pos] = e;
    }
}

// weight convert+transpose: src f32 [K][H] -> dst bf16 [H][KP]; gridDim.y = layer
__global__ void wconv_k(const float* __restrict__ src, u16* __restrict__ dst,
                        int K, int KP, int H){
    int idx = blockIdx.x*blockDim.x + threadIdx.x;
    if (idx >= H*KP) return;
    const int l = blockIdx.y;
    src += (size_t)l*K*H;  dst += (size_t)l*H*KP;
    int c = idx / KP, k = idx - c*KP;
    dst[idx] = (k < K) ? (u16)bfr(src[k*H + c]) : (u16)0;
}

// ---------------- fp32 matvec core (input/final kernels only) ----------------
__device__ __forceinline__ void mv_acc(const float* sT, int krows,
        const float* __restrict__ W, int c0, int eg, float acc[4][8])
{
    const float* Wp = W + c0;
    #pragma unroll 2
    for (int k=0; k<krows; ++k) {
        const float4 sv = *(const float4*)(sT + k*SROW + eg*4);
        const float4 wa = *(const float4*)(Wp + k*HD);
        const float4 wb = *(const float4*)(Wp + k*HD + 4);
        const float s[4] = {sv.x, sv.y, sv.z, sv.w};
        const float w[8] = {wa.x,wa.y,wa.z,wa.w, wb.x,wb.y,wb.z,wb.w};
        #pragma unroll
        for (int i=0;i<4;++i)
            #pragma unroll
            for (int j=0;j<8;++j)
                acc[i][j] = fmaf(s[i], w[j], acc[i][j]);
    }
}

__device__ __forceinline__ void stage_rows(float* smem, const float* __restrict__ base,
                                           const int* rowsLDS, int tid)
{
    const int e_lo = tid>>3, kq = tid&7;
    #pragma unroll
    for (int half=0; half<2; ++half) {
        const int e = e_lo + 32*half;
        const int row = rowsLDS[e];
        const float* p = base + (size_t)row*HD + kq*4;
        #pragma unroll
        for (int q=0; q<4; ++q) {
            const float4 v = *(const float4*)(p + q*32);
            const int kb = 4*kq + 32*q;
            smem[(kb+0)*SROW + e] = v.x;
            smem[(kb+1)*SROW + e] = v.y;
            smem[(kb+2)*SROW + e] = v.z;
            smem[(kb+3)*SROW + e] = v.w;
        }
    }
}

// ---------------- input MLP: h = relu(relu(x@W0+b0)@W1+b1); also bf16 mirror ----
__global__ __launch_bounds__(BLK) void input_mlp_k(
    const float* __restrict__ x,
    const float* __restrict__ W0, const float* __restrict__ b0,
    const float* __restrict__ W1, const float* __restrict__ b1,
    float* __restrict__ h, u16* __restrict__ hb)
{
    __shared__ float smem[130*SROW];
    const int tid = threadIdx.x;
    const int n0 = blockIdx.x * TE;

    #pragma unroll
    for (int it=0; it<(HD*TE)/BLK; ++it) {
        int task = it*BLK + tid;
        int e = task & (TE-1);
        int c = task >> 6;
        int n = n0 + e; if (n >= NN) n = NN-1;
        float x0 = x[n*2+0], x1 = x[n*2+1];
        smem[c*SROW + e] = fmaxf(fmaf(x0, W0[c], fmaf(x1, W0[HD+c], b0[c])), 0.0f);
    }
    __syncthreads();

    const int cg = tid & 15, eg = tid >> 4, c0 = cg*8;
    float acc[4][8];
    #pragma unroll
    for (int j=0;j<8;++j){ float bv=b1[c0+j];
        #pragma unroll
        for (int i=0;i<4;++i) acc[i][j]=bv; }
    mv_acc(smem, HD, W1, c0, eg, acc);

    #pragma unroll
    for (int i=0;i<4;++i){
        int n = n0 + eg*4 + i;
        if (n < NN) {
            float4 r0, r1;
            r0.x=fmaxf(acc[i][0],0.f); r0.y=fmaxf(acc[i][1],0.f);
            r0.z=fmaxf(acc[i][2],0.f); r0.w=fmaxf(acc[i][3],0.f);
            r1.x=fmaxf(acc[i][4],0.f); r1.y=fmaxf(acc[i][5],0.f);
            r1.z=fmaxf(acc[i][6],0.f); r1.w=fmaxf(acc[i][7],0.f);
            *(float4*)&h[(size_t)n*HD + c0]     = r0;
            *(float4*)&h[(size_t)n*HD + c0 + 4] = r1;
            uint4 pk;
            pk.x = bfr(r0.x)|(bfr(r0.y)<<16); pk.y = bfr(r0.z)|(bfr(r0.w)<<16);
            pk.z = bfr(r1.x)|(bfr(r1.y)<<16); pk.w = bfr(r1.z)|(bfr(r1.w)<<16);
            *(uint4*)&hb[(size_t)n*HD + c0] = pk;
        }
    }
}

// ===== MFMA fused edge-MLP + mean-aggregate + node-update =====
// Async-stage split (T14): chunk i+1's eidx->src->hb gather chain is issued
// during chunk i's GEMMs into registers; staging barrier only waits on ds_write.
// src broadcast via __shfl (no LDS, no extra barrier). 4 barriers/chunk.
__global__ __launch_bounds__(BLK, 3) void edge_node_kernel(
    const float* __restrict__ h, const u16* __restrict__ hb,
    const float* __restrict__ ea,
    const int* __restrict__ src, const int* __restrict__ eidx,
    const int* __restrict__ off, const float* __restrict__ rd,
    const u16* __restrict__ W1aT, const float* __restrict__ b1a,
    const u16* __restrict__ W1bT, const float* __restrict__ b1b,
    const u16* __restrict__ W2aT, const float* __restrict__ b2a,
    const u16* __restrict__ W2bT, const float* __restrict__ b2b,
    float* __restrict__ rbuf)
{
    __shared__ char bufA[TE*ASTR];   // feature tile [64][168] bf16 (K up to 160)
    __shared__ char bufB[TE*BSTR];   // m1 / m2 / u tile [64][136] bf16

    const int tid = threadIdx.x;
    const int lane = tid & 63;
    const int l15 = lane & 15, lhi = lane >> 4;     // D: col=l15, row=lhi*4+reg
    const int w = tid >> 6;                          // wave 0..3 -> c-tiles 2w,2w+1
    const int n0 = blockIdx.x * TE;
    const int cg = tid & 15, eg = tid >> 4, c0 = cg*8;   // reduce mapping
    const int myrow = tid >> 2;                      // row this thread stages (=16w+(lane>>2))
    const int p = tid & 3;                           // quarter-row part
    const int rowL = 16*w + l15;                     // row whose indices this lane loads
    const int bl = lane >> 2;                        // shfl broadcast source lane

    // zero bufA row k-tail [256,336) once (GEMM1 pad k in [130,160))
    for (int idx = tid; idx < TE*5; idx += BLK){
        const int r = idx/5, q = idx - r*5;
        *(uint4*)(bufA + r*ASTR + 256 + q*16) = make_uint4(0u,0u,0u,0u);
    }

    int o[5];
    #pragma unroll
    for (int i=0;i<5;++i){
        int n = n0 + eg*4 + i; if (n > NN) n = NN;
        o[i] = off[n];
    }
    const int S0 = off[n0];
    const int nEnd = (n0 + TE < NN) ? (n0 + TE) : NN;
    const int S1 = off[nEnd];

    float nacc[4][8];
    #pragma unroll
    for (int i=0;i<4;++i)
        #pragma unroll
        for (int j=0;j<8;++j) nacc[i][j]=0.f;

    // ---- prologue: prefetch chunk 0 gather into registers ----
    uint4 g0, g1, g2, g3;
    unsigned eaw = 0;
    {
        int slot = S0 + rowL; if (slot > NE-1) slot = NE-1;
        const int et  = eidx[slot];
        const int svo = src[et];
        const int sv  = __shfl(svo, bl);
        const int etr = __shfl(et,  bl);
        const uint4* sp = (const uint4*)(hb + (size_t)sv*HD);
        g0 = sp[p*4+0]; g1 = sp[p*4+1]; g2 = sp[p*4+2]; g3 = sp[p*4+3];
        if (p == 0){
            const float2 a = *(const float2*)&ea[(size_t)etr*2];
            eaw = bfr(a.x) | (bfr(a.y)<<16);
        }
    }
    __syncthreads();   // tail-zero visible before first stage

    for (int cs = S0; cs < S1; cs += TE) {
        // stage registers -> bufA (write-late half of T14)
        {
            uint4* dp = (uint4*)(bufA + myrow*ASTR + p*64);
            dp[0]=g0; dp[1]=g1; dp[2]=g2; dp[3]=g3;
            if (p == 0) *(unsigned*)(bufA + myrow*ASTR + 256) = eaw;
        }
        // issue next chunk's first-level index load (issue-early half)
        int slot_n = cs + TE + rowL; if (slot_n > NE-1) slot_n = NE-1;
        const int et_n = eidx[slot_n];
        __syncthreads();                               // BAR A: tile staged

        // ---- GEMM1: m1[c][e] = W1a^T(160k) x feat ----
        f32x4 acc1[2][4];
        #pragma unroll
        for (int cc=0; cc<2; ++cc){
            const float4 bv = *(const float4*)&b1a[(2*w+cc)*16 + lhi*4];
            #pragma unroll
            for (int te=0; te<4; ++te){
                acc1[cc][te][0]=bv.x; acc1[cc][te][1]=bv.y;
                acc1[cc][te][2]=bv.z; acc1[cc][te][3]=bv.w;
            }
        }
        #pragma unroll
        for (int kk=0; kk<5; ++kk){
            const bf16x8 a0 = *(const bf16x8*)(W1aT + ((2*w  )*16 + l15)*160 + kk*32 + lhi*8);
            const bf16x8 a1 = *(const bf16x8*)(W1aT + ((2*w+1)*16 + l15)*160 + kk*32 + lhi*8);
            #pragma unroll
            for (int te=0; te<4; ++te){
                const bf16x8 bb = *(const bf16x8*)(bufA + (te*16+l15)*ASTR + kk*64 + lhi*16);
                acc1[0][te] = MFMA16(a0, bb, acc1[0][te], 0,0,0);
                acc1[1][te] = MFMA16(a1, bb, acc1[1][te], 0,0,0);
            }
        }
        const int src_n = src[et_n];                   // second-level index load
        #pragma unroll
        for (int cc=0; cc<2; ++cc){
            #pragma unroll
            for (int te=0; te<4; ++te){
                uint2 pk;
                pk.x = bfr(fmaxf(acc1[cc][te][0],0.f)) | (bfr(fmaxf(acc1[cc][te][1],0.f))<<16);
                pk.y = bfr(fmaxf(acc1[cc][te][2],0.f)) | (bfr(fmaxf(acc1[cc][te][3],0.f))<<16);
                *(uint2*)(bufB + (te*16+l15)*BSTR + (2*w+cc)*32 + lhi*8) = pk;
            }
        }
        __syncthreads();                               // BAR B: m1 ready

        // ---- GEMM2: m2[c][e] = W1b^T(128k) x m1 ----
        f32x4 acc2[2][4];
        #pragma unroll
        for (int cc=0; cc<2; ++cc){
            const float4 bv = *(const float4*)&b1b[(2*w+cc)*16 + lhi*4];
            #pragma unroll
            for (int te=0; te<4; ++te){
                acc2[cc][te][0]=bv.x; acc2[cc][te][1]=bv.y;
                acc2[cc][te][2]=bv.z; acc2[cc][te][3]=bv.w;
            }
        }
        #pragma unroll
        for (int kk=0; kk<4; ++kk){
            const bf16x8 a0 = *(const bf16x8*)(W1bT + ((2*w  )*16 + l15)*128 + kk*32 + lhi*8);
            const bf16x8 a1 = *(const bf16x8*)(W1bT + ((2*w+1)*16 + l15)*128 + kk*32 + lhi*8);
            #pragma unroll
            for (int te=0; te<4; ++te){
                const bf16x8 bb = *(const bf16x8*)(bufB + (te*16+l15)*BSTR + kk*64 + lhi*16);
                acc2[0][te] = MFMA16(a0, bb, acc2[0][te], 0,0,0);
                acc2[1][te] = MFMA16(a1, bb, acc2[1][te], 0,0,0);
            }
        }
        // prefetch next chunk's gather into registers (overlaps BAR C/D + reduce)
        {
            const int sv  = __shfl(src_n, bl);
            const int etr = __shfl(et_n,  bl);
            const uint4* sp = (const uint4*)(hb + (size_t)sv*HD);
            g0 = sp[p*4+0]; g1 = sp[p*4+1]; g2 = sp[p*4+2]; g3 = sp[p*4+3];
            if (p == 0){
                const float2 a = *(const float2*)&ea[(size_t)etr*2];
                eaw = bfr(a.x) | (bfr(a.y)<<16);
            }
        }
        __syncthreads();                               // BAR C: m1 consumed
        #pragma unroll
        for (int cc=0; cc<2; ++cc){
            #pragma unroll
            for (int te=0; te<4; ++te){
                uint2 pk;
                pk.x = bfr(fmaxf(acc2[cc][te][0],0.f)) | (bfr(fmaxf(acc2[cc][te][1],0.f))<<16);
                pk.y = bfr(fmaxf(acc2[cc][te][2],0.f)) | (bfr(fmaxf(acc2[cc][te][3],0.f))<<16);
                *(uint2*)(bufB + (te*16+l15)*BSTR + (2*w+cc)*32 + lhi*8) = pk;
            }
        }
        __syncthreads();                               // BAR D: m2 ready

        // segment-reduce owned nodes' slots into registers
        #pragma unroll
        for (int i=0;i<4;++i){
            int lo = o[i]   > cs      ? o[i]   : cs;
            int hi = o[i+1] < cs + TE ? o[i+1] : cs + TE;
            for (int s = lo; s < hi; ++s){
                const uint4 v = *(const uint4*)(bufB + (s-cs)*BSTR + cg*16);
                nacc[i][0] += bf2f(v.x&0xffffu); nacc[i][1] += bf2f(v.x>>16);
                nacc[i][2] += bf2f(v.y&0xffffu); nacc[i][3] += bf2f(v.y>>16);
                nacc[i][4] += bf2f(v.z&0xffffu); nacc[i][5] += bf2f(v.z>>16);
                nacc[i][6] += bf2f(v.w&0xffffu); nacc[i][7] += bf2f(v.w>>16);
            }
        }
    }

    // ---- node update: u = relu(W2a^T.[h;agg]); r = h + sigm(W2b^T.u) ----
    #pragma unroll
    for (int i=0;i<4;++i){
        const int n = n0 + eg*4 + i;
        const float rdv = (n < NN) ? rd[n] : 0.f;
        #pragma unroll
        for (int j=0;j<8;++j) nacc[i][j] *= rdv;
    }
    __syncthreads();                                   // chunk loop fully drained
    {   // stage hb rows n0..n0+63
        int n = n0 + myrow; if (n >= NN) n = NN-1;
        const uint4* sp = (const uint4*)(hb + (size_t)n*HD);
        uint4* dp = (uint4*)(bufA + myrow*ASTR + p*64);
        #pragma unroll
        for (int q=0;q<4;++q) dp[q] = sp[p*4+q];
    }
    __syncthreads();

    f32x4 accN[2][4];
    #pragma unroll
    for (int cc=0; cc<2; ++cc){
        const float4 bv = *(const float4*)&b2a[(2*w+cc)*16 + lhi*4];
        #pragma unroll
        for (int te=0; te<4; ++te){
            accN[cc][te][0]=bv.x; accN[cc][te][1]=bv.y;
            accN[cc][te][2]=bv.z; accN[cc][te][3]=bv.w;
        }
    }
    #pragma unroll
    for (int kk=0; kk<4; ++kk){                         // K-half 1: h
        const bf16x8 a0 = *(const bf16x8*)(W2aT + ((2*w  )*16 + l15)*256 + kk*32 + lhi*8);
        const bf16x8 a1 = *(const bf16x8*)(W2aT + ((2*w+1)*16 + l15)*256 + kk*32 + lhi*8);
        #pragma unroll
        for (int te=0; te<4; ++te){
            const bf16x8 bb = *(const bf16x8*)(bufA + (te*16+l15)*ASTR + kk*64 + lhi*16);
            accN[0][te] = MFMA16(a0, bb, accN[0][te], 0,0,0);
            accN[1][te] = MFMA16(a1, bb, accN[1][te], 0,0,0);
        }
    }
    __syncthreads();
    #pragma unroll
    for (int i=0;i<4;++i){                              // stage agg (bf16) over h tile
        uint4 pk;
        pk.x = bfr(nacc[i][0]) | (bfr(nacc[i][1])<<16);
        pk.y = bfr(nacc[i][2]) | (bfr(nacc[i][3])<<16);
        pk.z = bfr(nacc[i][4]) | (bfr(nacc[i][5])<<16);
        pk.w = bfr(nacc[i][6]) | (bfr(nacc[i][7])<<16);
        *(uint4*)(bufA + (eg*4+i)*ASTR + cg*16) = pk;
    }
    __syncthreads();
    #pragma unroll
    for (int kk=0; kk<4; ++kk){                         // K-half 2: agg
        const bf16x8 a0 = *(const bf16x8*)(W2aT + ((2*w  )*16 + l15)*256 + 128 + kk*32 + lhi*8);
        const bf16x8 a1 = *(const bf16x8*)(W2aT + ((2*w+1)*16 + l15)*256 + 128 + kk*32 + lhi*8);
        #pragma unroll
        for (int te=0; te<4; ++te){
            const bf16x8 bb = *(const bf16x8*)(bufA + (te*16+l15)*ASTR + kk*64 + lhi*16);
            accN[0][te] = MFMA16(a0, bb, accN[0][te], 0,0,0);
            accN[1][te] = MFMA16(a1, bb, accN[1][te], 0,0,0);
        }
    }
    #pragma unroll
    for (int cc=0; cc<2; ++cc){                         // u = relu -> bufB
        #pragma unroll
        for (int te=0; te<4; ++te){
            uint2 pk;
            pk.x = bfr(fmaxf(accN[cc][te][0],0.f)) | (bfr(fmaxf(accN[cc][te][1],0.f))<<16);
            pk.y = bfr(fmaxf(accN[cc][te][2],0.f)) | (bfr(fmaxf(accN[cc][te][3],0.f))<<16);
            *(uint2*)(bufB + (te*16+l15)*BSTR + (2*w+cc)*32 + lhi*8) = pk;
        }
    }
    __syncthreads();

    f32x4 accO[2][4];
    #pragma unroll
    for (int cc=0; cc<2; ++cc){
        const float4 bv = *(const float4*)&b2b[(2*w+cc)*16 + lhi*4];
        #pragma unroll
        for (int te=0; te<4; ++te){
            accO[cc][te][0]=bv.x; accO[cc][te][1]=bv.y;
            accO[cc][te][2]=bv.z; accO[cc][te][3]=bv.w;
        }
    }
    #pragma unroll
    for (int kk=0; kk<4; ++kk){
        const bf16x8 a0 = *(const bf16x8*)(W2bT + ((2*w  )*16 + l15)*128 + kk*32 + lhi*8);
        const bf16x8 a1 = *(const bf16x8*)(W2bT + ((2*w+1)*16 + l15)*128 + kk*32 + lhi*8);
        #pragma unroll
        for (int te=0; te<4; ++te){
            const bf16x8 bb = *(const bf16x8*)(bufB + (te*16+l15)*BSTR + kk*64 + lhi*16);
            accO[0][te] = MFMA16(a0, bb, accO[0][te], 0,0,0);
            accO[1][te] = MFMA16(a1, bb, accO[1][te], 0,0,0);
        }
    }
    #pragma unroll
    for (int cc=0; cc<2; ++cc){
        const int cbase = (2*w+cc)*16 + lhi*4;
        #pragma unroll
        for (int te=0; te<4; ++te){
            const int n = n0 + te*16 + l15;
            if (n < NN){
                const float4 hv = *(const float4*)&h[(size_t)n*HD + cbase];
                float4 r;
                r.x = hv.x + sigm(accO[cc][te][0]);
                r.y = hv.y + sigm(accO[cc][te][1]);
                r.z = hv.z + sigm(accO[cc][te][2]);
                r.w = hv.w + sigm(accO[cc][te][3]);
                *(float4*)&rbuf[(size_t)n*HD + cbase] = r;
            }
        }
    }
}

// ---------------- BN stats ----------------
__global__ void bn_stats_k(const float* __restrict__ r, float* __restrict__ bn){
    const int c = threadIdx.x & (HD-1);
    const int half = threadIdx.x >> 7;
    const int stride = gridDim.x * 2;
    float s = 0.f, ss = 0.f;
    for (int n = blockIdx.x*2 + half; n < NN; n += stride) {
        const float v = r[(size_t)n*HD + c];
        s += v; ss += v*v;
    }
    atomAddF(&bn[c], s);
    atomAddF(&bn[HD+c], ss);
}

// ---------------- BN normalize (writes f32 h + bf16 mirror) ----------------
__global__ void bn_norm_k(const float* __restrict__ r, const float* __restrict__ bn,
                          const float* __restrict__ gamma, const float* __restrict__ beta,
                          float* __restrict__ h, u16* __restrict__ hb){
    const int i = blockIdx.x*blockDim.x + threadIdx.x;  // float4 index
    const int n4 = NN*HD/4;
    if (i >= n4) return;
    const int c0 = (i*4) & (HD-1);
    float4 v = ((const float4*)r)[i];
    float* vp = (float*)&v;
    #pragma unroll
    for (int j=0;j<4;++j){
        const int c = c0 + j;
        const float mu  = bn[c] * (1.0f/NN);
        const float var = bn[HD+c] * (1.0f/NN) - mu*mu;
        const float sc  = rsqrtf(var + EPSV) * gamma[c];
        const float sh  = beta[c] - mu*sc;
        vp[j] = fmaf(vp[j], sc, sh);
    }
    ((float4*)h)[i] = v;
    uint2 pk;
    pk.x = bfr(vp[0]) | (bfr(vp[1])<<16);
    pk.y = bfr(vp[2]) | (bfr(vp[3])<<16);
    ((uint2*)hb)[i] = pk;
}

// ---------------- final MLP ----------------
__global__ __launch_bounds__(BLK) void final_kernel(
    const float* __restrict__ h,
    const float* __restrict__ Wf, const float* __restrict__ bf,
    const float* __restrict__ Wo, const float* __restrict__ bo,
    float* __restrict__ out)
{
    __shared__ float smem[130*SROW];
    __shared__ int s_src[TE];
    const int tid = threadIdx.x;
    const int n0 = blockIdx.x * TE;
    const int cg = tid & 15, eg = tid >> 4, c0 = cg*8;

    if (tid < TE) { int n = n0 + tid; s_src[tid] = (n < NN) ? n : NN-1; }
    __syncthreads();
    stage_rows(smem, h, s_src, tid);
    __syncthreads();

    float acc[4][8];
    #pragma unroll
    for (int j=0;j<8;++j){ float bv=bf[c0+j];
        #pragma unroll
        for (int i=0;i<4;++i) acc[i][j]=bv; }
    mv_acc(smem, HD, Wf, c0, eg, acc);
    __syncthreads();

    #pragma unroll
    for (int j=0;j<8;++j){
        float4 m0;
        m0.x=fmaxf(acc[0][j],0.f); m0.y=fmaxf(acc[1][j],0.f);
        m0.z=fmaxf(acc[2][j],0.f); m0.w=fmaxf(acc[3][j],0.f);
        *(float4*)&smem[(c0+j)*SROW + eg*4] = m0;
    }
    __syncthreads();

    const int e = tid >> 2, q = tid & 3;
    float s = 0.f;
    #pragma unroll
    for (int kk=0; kk<32; ++kk) {
        const int k = q*32 + kk;
        s = fmaf(smem[k*SROW + e], Wo[k], s);
    }
    s += __shfl_xor(s, 1);
    s += __shfl_xor(s, 2);
    const int n = n0 + e;
    if (q == 0 && n < NN)
        out[n] = sigm(s + bo[0]);
}

// ---------------- launch ----------------
extern "C" void kernel_launch(void* const* d_in, const int* in_sizes, int n_in,
                              void* d_out, int out_size, void* d_ws, size_t ws_size,
                              hipStream_t stream)
{
    const float* x    = (const float*)d_in[0];
    const float* ea   = (const float*)d_in[1];
    const int*   ei   = (const int*)d_in[2];
    const float* Win0 = (const float*)d_in[4];
    const float* bin0 = (const float*)d_in[5];
    const float* Win1 = (const float*)d_in[6];
    const float* bin1 = (const float*)d_in[7];
    const float* W1a  = (const float*)d_in[8];
    const float* b1a  = (const float*)d_in[9];
    const float* W1b  = (const float*)d_in[10];
    const float* b1b  = (const float*)d_in[11];
    const float* W2a  = (const float*)d_in[12];
    const float* b2a  = (const float*)d_in[13];
    const float* W2b  = (const float*)d_in[14];
    const float* b2b  = (const float*)d_in[15];
    const float* gmm  = (const float*)d_in[16];
    const float* bta  = (const float*)d_in[17];
    const float* Wf   = (const float*)d_in[18];
    const float* bfv  = (const float*)d_in[19];
    const float* Wo   = (const float*)d_in[20];
    const float* bo   = (const float*)d_in[21];
    float* out = (float*)d_out;

    char* p = (char*)d_ws;
    float* h     = (float*)p;  p += (size_t)NN*HD*4;
    float* rbuf  = (float*)p;  p += (size_t)NN*HD*4;
    u16*   hb    = (u16*)p;    p += (size_t)NN*HD*2;
    u16*   W1aT  = (u16*)p;    p += (size_t)3*128*160*2;
    u16*   W1bT  = (u16*)p;    p += (size_t)3*128*128*2;
    u16*   W2aT  = (u16*)p;    p += (size_t)3*128*256*2;
    u16*   W2bT  = (u16*)p;    p += (size_t)3*128*128*2;
    float* rd    = (float*)p;  p += (size_t)NN*4;
    float* bn    = (float*)p;  p += 256*4;
    int*   cnt   = (int*)p;    p += (size_t)NN*4;
    int*   fill  = (int*)p;    p += (size_t)NN*4;
    int*   off   = (int*)p;    p += (size_t)(NN+1)*4;
    int*   eidx  = (int*)p;

    const int* srcp = ei;
    const int* dstp = ei + NE;

    const int GN = (NN + TE - 1) / TE;     // 782
    const int G4 = (NN*HD/4 + 255) / 256;  // 6250

    // ---- CSR build ----
    zero_i_k<<<(2*NN+255)/256, 256, 0, stream>>>(cnt, 2*NN);
    count_k<<<(NE+255)/256, 256, 0, stream>>>(dstp, cnt);
    scan_k<<<1, 1024, 0, stream>>>(cnt, off);
    rdenom_k<<<(NN+255)/256, 256, 0, stream>>>(cnt, rd);
    fill_k<<<(NE+255)/256, 256, 0, stream>>>(dstp, off, fill, eidx);

    // ---- weight convert/transpose to bf16 [c][k] (one launch per tensor, y=layer) ----
    wconv_k<<<dim3((128*160+255)/256,3), 256, 0, stream>>>(W1a, W1aT, 130, 160, 128);
    wconv_k<<<dim3((128*128+255)/256,3), 256, 0, stream>>>(W1b, W1bT, 128, 128, 128);
    wconv_k<<<dim3((128*256+255)/256,3), 256, 0, stream>>>(W2a, W2aT, 256, 256, 128);
    wconv_k<<<dim3((128*128+255)/256,3), 256, 0, stream>>>(W2b, W2bT, 128, 128, 128);

    input_mlp_k<<<GN, BLK, 0, stream>>>(x, Win0, bin0, Win1, bin1, h, hb);

    for (int l = 0; l < 3; ++l) {
        zero_bn_k<<<1, 256, 0, stream>>>(bn);
        edge_node_kernel<<<GN, BLK, 0, stream>>>(h, hb, ea, srcp, eidx, off, rd,
            W1aT + (size_t)l*128*160, b1a + l*HD,
            W1bT + (size_t)l*128*128, b1b + l*HD,
            W2aT + (size_t)l*128*256, b2a + l*HD,
            W2bT + (size_t)l*128*128, b2b + l*HD, rbuf);
        bn_stats_k<<<400, 256, 0, stream>>>(rbuf, bn);
        bn_norm_k<<<G4, 256, 0, stream>>>(rbuf, bn, gmm + l*HD, bta + l*HD, h, hb);
    }

    final_kernel<<<GN, BLK, 0, stream>>>(h, Wf, bfv, Wo, bo, out);
}

// Round 10
// 1164.518 us; speedup vs baseline: 1.3574x; 1.3574x over previous
//
#include <hip/hip_runtime.h>
#include <hip/hip_bf16.h>

#define NN 50000
#define NE 800000
#define HD 128
#define EPSV 1e-5f
#define TE 64
#define BLK 256
#define SROW 68          // fp32 LDS row stride for input/final kernels
#define ASTR 336         // bufA row stride bytes: 168 bf16
#define BSTR 272         // bufB row stride bytes: 136 bf16

typedef unsigned short u16;
typedef __attribute__((ext_vector_type(8))) short bf16x8;
typedef __attribute__((ext_vector_type(4))) float f32x4;
#define MFMA16 __builtin_amdgcn_mfma_f32_16x16x32_bf16

__device__ __forceinline__ float sigm(float x){ return 1.0f/(1.0f+__expf(-x)); }
__device__ __forceinline__ void atomAddF(float* p, float v){ unsafeAtomicAdd(p, v); }
__device__ __forceinline__ unsigned bfr(float x){           // f32 -> bf16 bits (RNE)
    unsigned u = __float_as_uint(x);
    return (u + 0x7FFFu + ((u>>16)&1u)) >> 16;
}
__device__ __forceinline__ float bf2f(unsigned u){ return __uint_as_float(u<<16); }

// ---------------- small utility kernels ----------------
__global__ void zero_i_k(int* __restrict__ p, int n){
    int i = blockIdx.x*blockDim.x + threadIdx.x;
    if (i < n) p[i] = 0;
}

__global__ void zero_agg_bn_k(float4* __restrict__ agg4, int n4, float* __restrict__ bn){
    int i = blockIdx.x*blockDim.x + threadIdx.x;
    if (i < n4) agg4[i] = make_float4(0.f,0.f,0.f,0.f);
    if (i < 256) bn[i] = 0.0f;
}

__global__ void count_k(const int* __restrict__ dst, int* __restrict__ cnt){
    int e = blockIdx.x*blockDim.x + threadIdx.x;
    if (e < NE) atomicAdd(&cnt[dst[e]], 1);
}
__global__ void rdenom_k(const int* __restrict__ cnt, float* __restrict__ rd){
    int i = blockIdx.x*blockDim.x + threadIdx.x;
    if (i < NN) rd[i] = 1.0f / fmaxf((float)cnt[i], 1.0f);
}

// single-block exclusive scan over NN ints -> CSR offsets; off[NN] = NE
__global__ __launch_bounds__(1024) void scan_k(const int* __restrict__ cnt, int* __restrict__ off){
    __shared__ int s[1024];
    __shared__ int carryS;
    const int tid = threadIdx.x;
    if (tid == 0) carryS = 0;
    __syncthreads();
    const int NCH = (NN + 1023) / 1024;
    for (int ch = 0; ch < NCH; ++ch){
        const int i = ch*1024 + tid;
        const int v = (i < NN) ? cnt[i] : 0;
        s[tid] = v;
        __syncthreads();
        #pragma unroll
        for (int ofs = 1; ofs < 1024; ofs <<= 1){
            int t = (tid >= ofs) ? s[tid-ofs] : 0;
            __syncthreads();
            s[tid] += t;
            __syncthreads();
        }
        const int carry = carryS;
        if (i < NN) off[i] = carry + s[tid] - v;
        __syncthreads();
        if (tid == 1023) carryS = carry + s[1023];
        __syncthreads();
    }
    if (tid == 0) off[NN] = NE;
}

__global__ void fill_k(const int* __restrict__ dst, const int* __restrict__ off,
                       int* __restrict__ fill, int* __restrict__ eidx,
                       int* __restrict__ sdst){
    int e = blockIdx.x*blockDim.x + threadIdx.x;
    if (e < NE){
        int d = dst[e];
        int pos = atomicAdd(&fill[d], 1);
        int slot = off[d] + pos;
        eidx[slot] = e;
        sdst[slot] = d;
    }
}

// weight convert+transpose: src f32 [K][H] -> dst bf16 [H][KP]; gridDim.y = layer
__global__ void wconv_k(const float* __restrict__ src, u16* __restrict__ dst,
                        int K, int KP, int H){
    int idx = blockIdx.x*blockDim.x + threadIdx.x;
    if (idx >= H*KP) return;
    const int l = blockIdx.y;
    src += (size_t)l*K*H;  dst += (size_t)l*H*KP;
    int c = idx / KP, k = idx - c*KP;
    dst[idx] = (k < K) ? (u16)bfr(src[k*H + c]) : (u16)0;
}

// ---------------- fp32 matvec core (input/final kernels only) ----------------
__device__ __forceinline__ void mv_acc(const float* sT, int krows,
        const float* __restrict__ W, int c0, int eg, float acc[4][8])
{
    const float* Wp = W + c0;
    #pragma unroll 2
    for (int k=0; k<krows; ++k) {
        const float4 sv = *(const float4*)(sT + k*SROW + eg*4);
        const float4 wa = *(const float4*)(Wp + k*HD);
        const float4 wb = *(const float4*)(Wp + k*HD + 4);
        const float s[4] = {sv.x, sv.y, sv.z, sv.w};
        const float w[8] = {wa.x,wa.y,wa.z,wa.w, wb.x,wb.y,wb.z,wb.w};
        #pragma unroll
        for (int i=0;i<4;++i)
            #pragma unroll
            for (int j=0;j<8;++j)
                acc[i][j] = fmaf(s[i], w[j], acc[i][j]);
    }
}

__device__ __forceinline__ void stage_rows(float* smem, const float* __restrict__ base,
                                           const int* rowsLDS, int tid)
{
    const int e_lo = tid>>3, kq = tid&7;
    #pragma unroll
    for (int half=0; half<2; ++half) {
        const int e = e_lo + 32*half;
        const int row = rowsLDS[e];
        const float* p = base + (size_t)row*HD + kq*4;
        #pragma unroll
        for (int q=0; q<4; ++q) {
            const float4 v = *(const float4*)(p + q*32);
            const int kb = 4*kq + 32*q;
            smem[(kb+0)*SROW + e] = v.x;
            smem[(kb+1)*SROW + e] = v.y;
            smem[(kb+2)*SROW + e] = v.z;
            smem[(kb+3)*SROW + e] = v.w;
        }
    }
}

// ---------------- input MLP: h = relu(relu(x@W0+b0)@W1+b1); also bf16 mirror ----
__global__ __launch_bounds__(BLK) void input_mlp_k(
    const float* __restrict__ x,
    const float* __restrict__ W0, const float* __restrict__ b0,
    const float* __restrict__ W1, const float* __restrict__ b1,
    float* __restrict__ h, u16* __restrict__ hb)
{
    __shared__ float smem[130*SROW];
    const int tid = threadIdx.x;
    const int n0 = blockIdx.x * TE;

    #pragma unroll
    for (int it=0; it<(HD*TE)/BLK; ++it) {
        int task = it*BLK + tid;
        int e = task & (TE-1);
        int c = task >> 6;
        int n = n0 + e; if (n >= NN) n = NN-1;
        float x0 = x[n*2+0], x1 = x[n*2+1];
        smem[c*SROW + e] = fmaxf(fmaf(x0, W0[c], fmaf(x1, W0[HD+c], b0[c])), 0.0f);
    }
    __syncthreads();

    const int cg = tid & 15, eg = tid >> 4, c0 = cg*8;
    float acc[4][8];
    #pragma unroll
    for (int j=0;j<8;++j){ float bv=b1[c0+j];
        #pragma unroll
        for (int i=0;i<4;++i) acc[i][j]=bv; }
    mv_acc(smem, HD, W1, c0, eg, acc);

    #pragma unroll
    for (int i=0;i<4;++i){
        int n = n0 + eg*4 + i;
        if (n < NN) {
            float4 r0, r1;
            r0.x=fmaxf(acc[i][0],0.f); r0.y=fmaxf(acc[i][1],0.f);
            r0.z=fmaxf(acc[i][2],0.f); r0.w=fmaxf(acc[i][3],0.f);
            r1.x=fmaxf(acc[i][4],0.f); r1.y=fmaxf(acc[i][5],0.f);
            r1.z=fmaxf(acc[i][6],0.f); r1.w=fmaxf(acc[i][7],0.f);
            *(float4*)&h[(size_t)n*HD + c0]     = r0;
            *(float4*)&h[(size_t)n*HD + c0 + 4] = r1;
            uint4 pk;
            pk.x = bfr(r0.x)|(bfr(r0.y)<<16); pk.y = bfr(r0.z)|(bfr(r0.w)<<16);
            pk.z = bfr(r1.x)|(bfr(r1.y)<<16); pk.w = bfr(r1.z)|(bfr(r1.w)<<16);
            *(uint4*)&hb[(size_t)n*HD + c0] = pk;
        }
    }
}

// ===== edge-centric message kernel: one block per 64-slot chunk =====
// m = relu(W1b.relu(W1a.[h_src;ea])); segmented-sum over dst-sorted slots.
// Interior nodes (full CSR range inside chunk): direct store (block-exclusive).
// Boundary nodes (<=2 per block): f32 atomics. rd (mean) folded in.
__global__ __launch_bounds__(BLK, 4) void edge_msg_kernel(
    const u16* __restrict__ hb, const float* __restrict__ ea,
    const int* __restrict__ src, const int* __restrict__ eidx,
    const int* __restrict__ sdst, const int* __restrict__ off,
    const float* __restrict__ rd,
    const u16* __restrict__ W1aT, const float* __restrict__ b1a,
    const u16* __restrict__ W1bT, const float* __restrict__ b1b,
    float* __restrict__ agg)
{
    __shared__ char bufA[TE*ASTR];   // feature tile [64][168] bf16
    __shared__ char bufB[TE*BSTR];   // m1 / m2 tile [64][136] bf16

    const int tid = threadIdx.x;
    const int lane = tid & 63;
    const int l15 = lane & 15, lhi = lane >> 4;     // D: col=l15, row=lhi*4+reg
    const int w = tid >> 6;                          // wave -> c-tiles 2w,2w+1
    const int s0 = blockIdx.x * TE;                  // NE % 64 == 0: no tail
    const int cg = tid & 15, c0 = cg*8;
    const int myrow = tid >> 2, p = tid & 3;
    const int rowL = 16*w + l15;
    const int bl = lane >> 2;

    // zero bufA k-tail [256,336) (GEMM1 pad k in [130,160))
    for (int idx = tid; idx < TE*5; idx += BLK){
        const int r = idx/5, q = idx - r*5;
        *(uint4*)(bufA + r*ASTR + 256 + q*16) = make_uint4(0u,0u,0u,0u);
    }

    // gather-stage hb[src] rows + edge_attr (src broadcast via shfl)
    {
        const int et  = eidx[s0 + rowL];
        const int sv0 = src[et];
        const int sv  = __shfl(sv0, bl);
        const int etr = __shfl(et,  bl);
        const uint4* sp = (const uint4*)(hb + (size_t)sv*HD);
        uint4* dp = (uint4*)(bufA + myrow*ASTR + p*64);
        #pragma unroll
        for (int q=0;q<4;++q) dp[q] = sp[p*4+q];
        if (p == 0){
            const float2 a = *(const float2*)&ea[(size_t)etr*2];
            *(unsigned*)(bufA + myrow*ASTR + 256) = bfr(a.x) | (bfr(a.y)<<16);
        }
    }
    __syncthreads();                               // BAR 1: tile staged

    // ---- GEMM1: m1[c][e] = W1a^T(160k) x feat ----
    f32x4 acc1[2][4];
    #pragma unroll
    for (int cc=0; cc<2; ++cc){
        const float4 bv = *(const float4*)&b1a[(2*w+cc)*16 + lhi*4];
        #pragma unroll
        for (int te=0; te<4; ++te){
            acc1[cc][te][0]=bv.x; acc1[cc][te][1]=bv.y;
            acc1[cc][te][2]=bv.z; acc1[cc][te][3]=bv.w;
        }
    }
    #pragma unroll
    for (int kk=0; kk<5; ++kk){
        const bf16x8 a0 = *(const bf16x8*)(W1aT + ((2*w  )*16 + l15)*160 + kk*32 + lhi*8);
        const bf16x8 a1 = *(const bf16x8*)(W1aT + ((2*w+1)*16 + l15)*160 + kk*32 + lhi*8);
        #pragma unroll
        for (int te=0; te<4; ++te){
            const bf16x8 bb = *(const bf16x8*)(bufA + (te*16+l15)*ASTR + kk*64 + lhi*16);
            acc1[0][te] = MFMA16(a0, bb, acc1[0][te], 0,0,0);
            acc1[1][te] = MFMA16(a1, bb, acc1[1][te], 0,0,0);
        }
    }
    #pragma unroll
    for (int cc=0; cc<2; ++cc){
        #pragma unroll
        for (int te=0; te<4; ++te){
            uint2 pk;
            pk.x = bfr(fmaxf(acc1[cc][te][0],0.f)) | (bfr(fmaxf(acc1[cc][te][1],0.f))<<16);
            pk.y = bfr(fmaxf(acc1[cc][te][2],0.f)) | (bfr(fmaxf(acc1[cc][te][3],0.f))<<16);
            *(uint2*)(bufB + (te*16+l15)*BSTR + (2*w+cc)*32 + lhi*8) = pk;
        }
    }
    __syncthreads();                               // BAR 2: m1 ready

    // ---- GEMM2: m2[c][e] = W1b^T(128k) x m1 ----
    f32x4 acc2[2][4];
    #pragma unroll
    for (int cc=0; cc<2; ++cc){
        const float4 bv = *(const float4*)&b1b[(2*w+cc)*16 + lhi*4];
        #pragma unroll
        for (int te=0; te<4; ++te){
            acc2[cc][te][0]=bv.x; acc2[cc][te][1]=bv.y;
            acc2[cc][te][2]=bv.z; acc2[cc][te][3]=bv.w;
        }
    }
    #pragma unroll
    for (int kk=0; kk<4; ++kk){
        const bf16x8 a0 = *(const bf16x8*)(W1bT + ((2*w  )*16 + l15)*128 + kk*32 + lhi*8);
        const bf16x8 a1 = *(const bf16x8*)(W1bT + ((2*w+1)*16 + l15)*128 + kk*32 + lhi*8);
        #pragma unroll
        for (int te=0; te<4; ++te){
            const bf16x8 bb = *(const bf16x8*)(bufB + (te*16+l15)*BSTR + kk*64 + lhi*16);
            acc2[0][te] = MFMA16(a0, bb, acc2[0][te], 0,0,0);
            acc2[1][te] = MFMA16(a1, bb, acc2[1][te], 0,0,0);
        }
    }
    __syncthreads();                               // BAR 3: m1 reads done
    #pragma unroll
    for (int cc=0; cc<2; ++cc){
        #pragma unroll
        for (int te=0; te<4; ++te){
            uint2 pk;
            pk.x = bfr(fmaxf(acc2[cc][te][0],0.f)) | (bfr(fmaxf(acc2[cc][te][1],0.f))<<16);
            pk.y = bfr(fmaxf(acc2[cc][te][2],0.f)) | (bfr(fmaxf(acc2[cc][te][3],0.f))<<16);
            *(uint2*)(bufB + (te*16+l15)*BSTR + (2*w+cc)*32 + lhi*8) = pk;
        }
    }
    __syncthreads();                               // BAR 4: m2 ready

    // ---- segmented reduce over dst-sorted slots ----
    // thread (cg, ng) handles channels c0..c0+7 of distinct node d0+ng, d0+ng+16, ...
    const int d0 = sdst[s0];
    const int d1 = sdst[s0 + TE - 1];
    const int ng = tid >> 4;
    for (int d = d0 + ng; d <= d1; d += 16){
        const int ob = off[d], oe = off[d+1];
        int lo = ob > s0 ? ob : s0;
        int hi = oe < s0 + TE ? oe : s0 + TE;
        if (lo >= hi) continue;                    // degree-0 gap node
        float s[8] = {0.f,0.f,0.f,0.f,0.f,0.f,0.f,0.f};
        for (int t = lo; t < hi; ++t){
            const uint4 v = *(const uint4*)(bufB + (t - s0)*BSTR + cg*16);
            s[0] += bf2f(v.x&0xffffu); s[1] += bf2f(v.x>>16);
            s[2] += bf2f(v.y&0xffffu); s[3] += bf2f(v.y>>16);
            s[4] += bf2f(v.z&0xffffu); s[5] += bf2f(v.z>>16);
            s[6] += bf2f(v.w&0xffffu); s[7] += bf2f(v.w>>16);
        }
        const float rdv = rd[d];
        #pragma unroll
        for (int j=0;j<8;++j) s[j] *= rdv;
        float* ap = &agg[(size_t)d*HD + c0];
        if (ob >= s0 && oe <= s0 + TE){            // interior: exclusive, direct store
            float4 a0 = make_float4(s[0],s[1],s[2],s[3]);
            float4 a1 = make_float4(s[4],s[5],s[6],s[7]);
            *(float4*)ap = a0; *(float4*)(ap+4) = a1;
        } else {                                   // boundary: atomic partial
            #pragma unroll
            for (int j=0;j<8;++j) atomAddF(ap+j, s[j]);
        }
    }
}

// ===== node update kernel: u = relu(W2a^T.[h;agg]); r = h + sigm(W2b^T.u) =====
__global__ __launch_bounds__(BLK, 4) void node_upd_kernel(
    const float* __restrict__ h, const u16* __restrict__ hb,
    const float* __restrict__ agg,
    const u16* __restrict__ W2aT, const float* __restrict__ b2a,
    const u16* __restrict__ W2bT, const float* __restrict__ b2b,
    float* __restrict__ rbuf)
{
    __shared__ char bufA[TE*ASTR];
    __shared__ char bufB[TE*BSTR];

    const int tid = threadIdx.x;
    const int lane = tid & 63;
    const int l15 = lane & 15, lhi = lane >> 4;
    const int w = tid >> 6;
    const int n0 = blockIdx.x * TE;
    const int myrow = tid >> 2, p = tid & 3;

    {   // stage hb rows n0..n0+63
        int n = n0 + myrow; if (n >= NN) n = NN-1;
        const uint4* sp = (const uint4*)(hb + (size_t)n*HD);
        uint4* dp = (uint4*)(bufA + myrow*ASTR + p*64);
        #pragma unroll
        for (int q=0;q<4;++q) dp[q] = sp[p*4+q];
    }
    __syncthreads();

    f32x4 accN[2][4];
    #pragma unroll
    for (int cc=0; cc<2; ++cc){
        const float4 bv = *(const float4*)&b2a[(2*w+cc)*16 + lhi*4];
        #pragma unroll
        for (int te=0; te<4; ++te){
            accN[cc][te][0]=bv.x; accN[cc][te][1]=bv.y;
            accN[cc][te][2]=bv.z; accN[cc][te][3]=bv.w;
        }
    }
    #pragma unroll
    for (int kk=0; kk<4; ++kk){                         // K-half 1: h
        const bf16x8 a0 = *(const bf16x8*)(W2aT + ((2*w  )*16 + l15)*256 + kk*32 + lhi*8);
        const bf16x8 a1 = *(const bf16x8*)(W2aT + ((2*w+1)*16 + l15)*256 + kk*32 + lhi*8);
        #pragma unroll
        for (int te=0; te<4; ++te){
            const bf16x8 bb = *(const bf16x8*)(bufA + (te*16+l15)*ASTR + kk*64 + lhi*16);
            accN[0][te] = MFMA16(a0, bb, accN[0][te], 0,0,0);
            accN[1][te] = MFMA16(a1, bb, accN[1][te], 0,0,0);
        }
    }
    __syncthreads();
    {   // stage agg rows (f32 -> bf16 pack); agg already mean-scaled
        int n = n0 + myrow; if (n >= NN) n = NN-1;
        const float4* sp = (const float4*)(agg + (size_t)n*HD + p*32);
        uint4* dp = (uint4*)(bufA + myrow*ASTR + p*64);
        #pragma unroll
        for (int q=0;q<4;++q){
            const float4 v0 = sp[q*2+0], v1 = sp[q*2+1];
            uint4 pk;
            pk.x = bfr(v0.x)|(bfr(v0.y)<<16); pk.y = bfr(v0.z)|(bfr(v0.w)<<16);
            pk.z = bfr(v1.x)|(bfr(v1.y)<<16); pk.w = bfr(v1.z)|(bfr(v1.w)<<16);
            dp[q] = pk;
        }
    }
    __syncthreads();
    #pragma unroll
    for (int kk=0; kk<4; ++kk){                         // K-half 2: agg
        const bf16x8 a0 = *(const bf16x8*)(W2aT + ((2*w  )*16 + l15)*256 + 128 + kk*32 + lhi*8);
        const bf16x8 a1 = *(const bf16x8*)(W2aT + ((2*w+1)*16 + l15)*256 + 128 + kk*32 + lhi*8);
        #pragma unroll
        for (int te=0; te<4; ++te){
            const bf16x8 bb = *(const bf16x8*)(bufA + (te*16+l15)*ASTR + kk*64 + lhi*16);
            accN[0][te] = MFMA16(a0, bb, accN[0][te], 0,0,0);
            accN[1][te] = MFMA16(a1, bb, accN[1][te], 0,0,0);
        }
    }
    #pragma unroll
    for (int cc=0; cc<2; ++cc){                         // u = relu -> bufB
        #pragma unroll
        for (int te=0; te<4; ++te){
            uint2 pk;
            pk.x = bfr(fmaxf(accN[cc][te][0],0.f)) | (bfr(fmaxf(accN[cc][te][1],0.f))<<16);
            pk.y = bfr(fmaxf(accN[cc][te][2],0.f)) | (bfr(fmaxf(accN[cc][te][3],0.f))<<16);
            *(uint2*)(bufB + (te*16+l15)*BSTR + (2*w+cc)*32 + lhi*8) = pk;
        }
    }
    __syncthreads();

    f32x4 accO[2][4];
    #pragma unroll
    for (int cc=0; cc<2; ++cc){
        const float4 bv = *(const float4*)&b2b[(2*w+cc)*16 + lhi*4];
        #pragma unroll
        for (int te=0; te<4; ++te){
            accO[cc][te][0]=bv.x; accO[cc][te][1]=bv.y;
            accO[cc][te][2]=bv.z; accO[cc][te][3]=bv.w;
        }
    }
    #pragma unroll
    for (int kk=0; kk<4; ++kk){
        const bf16x8 a0 = *(const bf16x8*)(W2bT + ((2*w  )*16 + l15)*128 + kk*32 + lhi*8);
        const bf16x8 a1 = *(const bf16x8*)(W2bT + ((2*w+1)*16 + l15)*128 + kk*32 + lhi*8);
        #pragma unroll
        for (int te=0; te<4; ++te){
            const bf16x8 bb = *(const bf16x8*)(bufB + (te*16+l15)*BSTR + kk*64 + lhi*16);
            accO[0][te] = MFMA16(a0, bb, accO[0][te], 0,0,0);
            accO[1][te] = MFMA16(a1, bb, accO[1][te], 0,0,0);
        }
    }
    #pragma unroll
    for (int cc=0; cc<2; ++cc){
        const int cbase = (2*w+cc)*16 + lhi*4;
        #pragma unroll
        for (int te=0; te<4; ++te){
            const int n = n0 + te*16 + l15;
            if (n < NN){
                const float4 hv = *(const float4*)&h[(size_t)n*HD + cbase];
                float4 r;
                r.x = hv.x + sigm(accO[cc][te][0]);
                r.y = hv.y + sigm(accO[cc][te][1]);
                r.z = hv.z + sigm(accO[cc][te][2]);
                r.w = hv.w + sigm(accO[cc][te][3]);
                *(float4*)&rbuf[(size_t)n*HD + cbase] = r;
            }
        }
    }
}

// ---------------- BN stats ----------------
__global__ void bn_stats_k(const float* __restrict__ r, float* __restrict__ bn){
    const int c = threadIdx.x & (HD-1);
    const int half = threadIdx.x >> 7;
    const int stride = gridDim.x * 2;
    float s = 0.f, ss = 0.f;
    for (int n = blockIdx.x*2 + half; n < NN; n += stride) {
        const float v = r[(size_t)n*HD + c];
        s += v; ss += v*v;
    }
    atomAddF(&bn[c], s);
    atomAddF(&bn[HD+c], ss);
}

// ---------------- BN normalize (writes f32 h + bf16 mirror) ----------------
__global__ void bn_norm_k(const float* __restrict__ r, const float* __restrict__ bn,
                          const float* __restrict__ gamma, const float* __restrict__ beta,
                          float* __restrict__ h, u16* __restrict__ hb){
    const int i = blockIdx.x*blockDim.x + threadIdx.x;  // float4 index
    const int n4 = NN*HD/4;
    if (i >= n4) return;
    const int c0 = (i*4) & (HD-1);
    float4 v = ((const float4*)r)[i];
    float* vp = (float*)&v;
    #pragma unroll
    for (int j=0;j<4;++j){
        const int c = c0 + j;
        const float mu  = bn[c] * (1.0f/NN);
        const float var = bn[HD+c] * (1.0f/NN) - mu*mu;
        const float sc  = rsqrtf(var + EPSV) * gamma[c];
        const float sh  = beta[c] - mu*sc;
        vp[j] = fmaf(vp[j], sc, sh);
    }
    ((float4*)h)[i] = v;
    uint2 pk;
    pk.x = bfr(vp[0]) | (bfr(vp[1])<<16);
    pk.y = bfr(vp[2]) | (bfr(vp[3])<<16);
    ((uint2*)hb)[i] = pk;
}

// ---------------- final MLP ----------------
__global__ __launch_bounds__(BLK) void final_kernel(
    const float* __restrict__ h,
    const float* __restrict__ Wf, const float* __restrict__ bf,
    const float* __restrict__ Wo, const float* __restrict__ bo,
    float* __restrict__ out)
{
    __shared__ float smem[130*SROW];
    __shared__ int s_src[TE];
    const int tid = threadIdx.x;
    const int n0 = blockIdx.x * TE;
    const int cg = tid & 15, eg = tid >> 4, c0 = cg*8;

    if (tid < TE) { int n = n0 + tid; s_src[tid] = (n < NN) ? n : NN-1; }
    __syncthreads();
    stage_rows(smem, h, s_src, tid);
    __syncthreads();

    float acc[4][8];
    #pragma unroll
    for (int j=0;j<8;++j){ float bv=bf[c0+j];
        #pragma unroll
        for (int i=0;i<4;++i) acc[i][j]=bv; }
    mv_acc(smem, HD, Wf, c0, eg, acc);
    __syncthreads();

    #pragma unroll
    for (int j=0;j<8;++j){
        float4 m0;
        m0.x=fmaxf(acc[0][j],0.f); m0.y=fmaxf(acc[1][j],0.f);
        m0.z=fmaxf(acc[2][j],0.f); m0.w=fmaxf(acc[3][j],0.f);
        *(float4*)&smem[(c0+j)*SROW + eg*4] = m0;
    }
    __syncthreads();

    const int e = tid >> 2, q = tid & 3;
    float s = 0.f;
    #pragma unroll
    for (int kk=0; kk<32; ++kk) {
        const int k = q*32 + kk;
        s = fmaf(smem[k*SROW + e], Wo[k], s);
    }
    s += __shfl_xor(s, 1);
    s += __shfl_xor(s, 2);
    const int n = n0 + e;
    if (q == 0 && n < NN)
        out[n] = sigm(s + bo[0]);
}

// ---------------- launch ----------------
extern "C" void kernel_launch(void* const* d_in, const int* in_sizes, int n_in,
                              void* d_out, int out_size, void* d_ws, size_t ws_size,
                              hipStream_t stream)
{
    const float* x    = (const float*)d_in[0];
    const float* ea   = (const float*)d_in[1];
    const int*   ei   = (const int*)d_in[2];
    const float* Win0 = (const float*)d_in[4];
    const float* bin0 = (const float*)d_in[5];
    const float* Win1 = (const float*)d_in[6];
    const float* bin1 = (const float*)d_in[7];
    const float* W1a  = (const float*)d_in[8];
    const float* b1a  = (const float*)d_in[9];
    const float* W1b  = (const float*)d_in[10];
    const float* b1b  = (const float*)d_in[11];
    const float* W2a  = (const float*)d_in[12];
    const float* b2a  = (const float*)d_in[13];
    const float* W2b  = (const float*)d_in[14];
    const float* b2b  = (const float*)d_in[15];
    const float* gmm  = (const float*)d_in[16];
    const float* bta  = (const float*)d_in[17];
    const float* Wf   = (const float*)d_in[18];
    const float* bfv  = (const float*)d_in[19];
    const float* Wo   = (const float*)d_in[20];
    const float* bo   = (const float*)d_in[21];
    float* out = (float*)d_out;

    char* p = (char*)d_ws;
    float* h     = (float*)p;  p += (size_t)NN*HD*4;
    float* rbuf  = (float*)p;  p += (size_t)NN*HD*4;
    float* agg   = (float*)p;  p += (size_t)NN*HD*4;
    u16*   hb    = (u16*)p;    p += (size_t)NN*HD*2;
    u16*   W1aT  = (u16*)p;    p += (size_t)3*128*160*2;
    u16*   W1bT  = (u16*)p;    p += (size_t)3*128*128*2;
    u16*   W2aT  = (u16*)p;    p += (size_t)3*128*256*2;
    u16*   W2bT  = (u16*)p;    p += (size_t)3*128*128*2;
    float* rd    = (float*)p;  p += (size_t)NN*4;
    float* bn    = (float*)p;  p += 256*4;
    int*   cnt   = (int*)p;    p += (size_t)NN*4;
    int*   fill  = (int*)p;    p += (size_t)NN*4;
    int*   off   = (int*)p;    p += (size_t)(NN+1)*4;
    int*   eidx  = (int*)p;    p += (size_t)NE*4;
    int*   sdst  = (int*)p;

    const int* srcp = ei;
    const int* dstp = ei + NE;

    const int GN = (NN + TE - 1) / TE;     // 782
    const int GE = NE / TE;                // 12500
    const int G4 = (NN*HD/4 + 255) / 256;  // 6250

    // ---- CSR build ----
    zero_i_k<<<(2*NN+255)/256, 256, 0, stream>>>(cnt, 2*NN);
    count_k<<<(NE+255)/256, 256, 0, stream>>>(dstp, cnt);
    scan_k<<<1, 1024, 0, stream>>>(cnt, off);
    rdenom_k<<<(NN+255)/256, 256, 0, stream>>>(cnt, rd);
    fill_k<<<(NE+255)/256, 256, 0, stream>>>(dstp, off, fill, eidx, sdst);

    // ---- weight convert/transpose to bf16 [c][k] ----
    wconv_k<<<dim3((128*160+255)/256,3), 256, 0, stream>>>(W1a, W1aT, 130, 160, 128);
    wconv_k<<<dim3((128*128+255)/256,3), 256, 0, stream>>>(W1b, W1bT, 128, 128, 128);
    wconv_k<<<dim3((128*256+255)/256,3), 256, 0, stream>>>(W2a, W2aT, 256, 256, 128);
    wconv_k<<<dim3((128*128+255)/256,3), 256, 0, stream>>>(W2b, W2bT, 128, 128, 128);

    input_mlp_k<<<GN, BLK, 0, stream>>>(x, Win0, bin0, Win1, bin1, h, hb);

    for (int l = 0; l < 3; ++l) {
        zero_agg_bn_k<<<G4, 256, 0, stream>>>((float4*)agg, NN*HD/4, bn);
        edge_msg_kernel<<<GE, BLK, 0, stream>>>(hb, ea, srcp, eidx, sdst, off, rd,
            W1aT + (size_t)l*128*160, b1a + l*HD,
            W1bT + (size_t)l*128*128, b1b + l*HD, agg);
        node_upd_kernel<<<GN, BLK, 0, stream>>>(h, hb, agg,
            W2aT + (size_t)l*128*256, b2a + l*HD,
            W2bT + (size_t)l*128*128, b2b + l*HD, rbuf);
        bn_stats_k<<<400, 256, 0, stream>>>(rbuf, bn);
        bn_norm_k<<<G4, 256, 0, stream>>>(rbuf, bn, gmm + l*HD, bta + l*HD, h, hb);
    }

    final_kernel<<<GN, BLK, 0, stream>>>(h, Wf, bfv, Wo, bo, out);
}

// Round 11
// 1047.532 us; speedup vs baseline: 1.5090x; 1.1117x over previous
//
#include <hip/hip_runtime.h>
#include <hip/hip_bf16.h>

#define NN 50000
#define NE 800000
#define HD 128
#define EPSV 1e-5f
#define TE 64
#define BLK 256
#define SROW 68          // fp32 LDS row stride for input/final kernels
#define ASTR 336         // edge tile row stride bytes: data[0,256) ea[256,260) zeros[260,336)
#define BSTR 272         // node_upd bufB row stride bytes

typedef unsigned short u16;
typedef __attribute__((ext_vector_type(8))) short bf16x8;
typedef __attribute__((ext_vector_type(4))) float f32x4;
#define MFMA16 __builtin_amdgcn_mfma_f32_16x16x32_bf16

__device__ __forceinline__ float sigm(float x){ return 1.0f/(1.0f+__expf(-x)); }
__device__ __forceinline__ void atomAddF(float* p, float v){ unsafeAtomicAdd(p, v); }
__device__ __forceinline__ unsigned bfr(float x){           // f32 -> bf16 bits (RNE)
    unsigned u = __float_as_uint(x);
    return (u + 0x7FFFu + ((u>>16)&1u)) >> 16;
}
__device__ __forceinline__ float bf2f(unsigned u){ return __uint_as_float(u<<16); }

// ---------------- small utility kernels ----------------
__global__ void zero_i_k(int* __restrict__ p, int n){
    int i = blockIdx.x*blockDim.x + threadIdx.x;
    if (i < n) p[i] = 0;
}

__global__ void zero_agg_bn_k(float4* __restrict__ agg4, int n4, float* __restrict__ bn){
    int i = blockIdx.x*blockDim.x + threadIdx.x;
    if (i < n4) agg4[i] = make_float4(0.f,0.f,0.f,0.f);
    if (i < 256) bn[i] = 0.0f;
}

__global__ void count_k(const int* __restrict__ dst, int* __restrict__ cnt){
    int e = blockIdx.x*blockDim.x + threadIdx.x;
    if (e < NE) atomicAdd(&cnt[dst[e]], 1);
}
__global__ void rdenom_k(const int* __restrict__ cnt, float* __restrict__ rd){
    int i = blockIdx.x*blockDim.x + threadIdx.x;
    if (i < NN) rd[i] = 1.0f / fmaxf((float)cnt[i], 1.0f);
}

// single-block exclusive scan over NN ints -> CSR offsets; off[NN] = NE
__global__ __launch_bounds__(1024) void scan_k(const int* __restrict__ cnt, int* __restrict__ off){
    __shared__ int s[1024];
    __shared__ int carryS;
    const int tid = threadIdx.x;
    if (tid == 0) carryS = 0;
    __syncthreads();
    const int NCH = (NN + 1023) / 1024;
    for (int ch = 0; ch < NCH; ++ch){
        const int i = ch*1024 + tid;
        const int v = (i < NN) ? cnt[i] : 0;
        s[tid] = v;
        __syncthreads();
        #pragma unroll
        for (int ofs = 1; ofs < 1024; ofs <<= 1){
            int t = (tid >= ofs) ? s[tid-ofs] : 0;
            __syncthreads();
            s[tid] += t;
            __syncthreads();
        }
        const int carry = carryS;
        if (i < NN) off[i] = carry + s[tid] - v;
        __syncthreads();
        if (tid == 1023) carryS = carry + s[1023];
        __syncthreads();
    }
    if (tid == 0) off[NN] = NE;
}

// bucket-fill: fold the src/ea indirection into slot-order arrays
// ssrc[slot]=src node, sea[slot]=bf16-packed edge_attr, sdst[slot]=dst node
__global__ void fill_k(const int* __restrict__ src, const int* __restrict__ dst,
                       const float* __restrict__ ea, const int* __restrict__ off,
                       int* __restrict__ fill, int* __restrict__ ssrc,
                       unsigned* __restrict__ sea, int* __restrict__ sdst){
    int e = blockIdx.x*blockDim.x + threadIdx.x;
    if (e < NE){
        int d = dst[e];
        int pos = atomicAdd(&fill[d], 1);
        int slot = off[d] + pos;
        ssrc[slot] = src[e];
        sdst[slot] = d;
        const float2 a = *(const float2*)&ea[(size_t)e*2];
        sea[slot] = bfr(a.x) | (bfr(a.y)<<16);
    }
}

// weight convert+transpose: src f32 [K][H] -> dst bf16 [H][KP]; gridDim.y = layer
__global__ void wconv_k(const float* __restrict__ src, u16* __restrict__ dst,
                        int K, int KP, int H){
    int idx = blockIdx.x*blockDim.x + threadIdx.x;
    if (idx >= H*KP) return;
    const int l = blockIdx.y;
    src += (size_t)l*K*H;  dst += (size_t)l*H*KP;
    int c = idx / KP, k = idx - c*KP;
    dst[idx] = (k < K) ? (u16)bfr(src[k*H + c]) : (u16)0;
}

// ---------------- fp32 matvec core (input/final kernels only) ----------------
__device__ __forceinline__ void mv_acc(const float* sT, int krows,
        const float* __restrict__ W, int c0, int eg, float acc[4][8])
{
    const float* Wp = W + c0;
    #pragma unroll 2
    for (int k=0; k<krows; ++k) {
        const float4 sv = *(const float4*)(sT + k*SROW + eg*4);
        const float4 wa = *(const float4*)(Wp + k*HD);
        const float4 wb = *(const float4*)(Wp + k*HD + 4);
        const float s[4] = {sv.x, sv.y, sv.z, sv.w};
        const float w[8] = {wa.x,wa.y,wa.z,wa.w, wb.x,wb.y,wb.z,wb.w};
        #pragma unroll
        for (int i=0;i<4;++i)
            #pragma unroll
            for (int j=0;j<8;++j)
                acc[i][j] = fmaf(s[i], w[j], acc[i][j]);
    }
}

__device__ __forceinline__ void stage_rows(float* smem, const float* __restrict__ base,
                                           const int* rowsLDS, int tid)
{
    const int e_lo = tid>>3, kq = tid&7;
    #pragma unroll
    for (int half=0; half<2; ++half) {
        const int e = e_lo + 32*half;
        const int row = rowsLDS[e];
        const float* p = base + (size_t)row*HD + kq*4;
        #pragma unroll
        for (int q=0; q<4; ++q) {
            const float4 v = *(const float4*)(p + q*32);
            const int kb = 4*kq + 32*q;
            smem[(kb+0)*SROW + e] = v.x;
            smem[(kb+1)*SROW + e] = v.y;
            smem[(kb+2)*SROW + e] = v.z;
            smem[(kb+3)*SROW + e] = v.w;
        }
    }
}

// ---------------- input MLP: h = relu(relu(x@W0+b0)@W1+b1); also bf16 mirror ----
__global__ __launch_bounds__(BLK) void input_mlp_k(
    const float* __restrict__ x,
    const float* __restrict__ W0, const float* __restrict__ b0,
    const float* __restrict__ W1, const float* __restrict__ b1,
    float* __restrict__ h, u16* __restrict__ hb)
{
    __shared__ float smem[130*SROW];
    const int tid = threadIdx.x;
    const int n0 = blockIdx.x * TE;

    #pragma unroll
    for (int it=0; it<(HD*TE)/BLK; ++it) {
        int task = it*BLK + tid;
        int e = task & (TE-1);
        int c = task >> 6;
        int n = n0 + e; if (n >= NN) n = NN-1;
        float x0 = x[n*2+0], x1 = x[n*2+1];
        smem[c*SROW + e] = fmaxf(fmaf(x0, W0[c], fmaf(x1, W0[HD+c], b0[c])), 0.0f);
    }
    __syncthreads();

    const int cg = tid & 15, eg = tid >> 4, c0 = cg*8;
    float acc[4][8];
    #pragma unroll
    for (int j=0;j<8;++j){ float bv=b1[c0+j];
        #pragma unroll
        for (int i=0;i<4;++i) acc[i][j]=bv; }
    mv_acc(smem, HD, W1, c0, eg, acc);

    #pragma unroll
    for (int i=0;i<4;++i){
        int n = n0 + eg*4 + i;
        if (n < NN) {
            float4 r0, r1;
            r0.x=fmaxf(acc[i][0],0.f); r0.y=fmaxf(acc[i][1],0.f);
            r0.z=fmaxf(acc[i][2],0.f); r0.w=fmaxf(acc[i][3],0.f);
            r1.x=fmaxf(acc[i][4],0.f); r1.y=fmaxf(acc[i][5],0.f);
            r1.z=fmaxf(acc[i][6],0.f); r1.w=fmaxf(acc[i][7],0.f);
            *(float4*)&h[(size_t)n*HD + c0]     = r0;
            *(float4*)&h[(size_t)n*HD + c0 + 4] = r1;
            uint4 pk;
            pk.x = bfr(r0.x)|(bfr(r0.y)<<16); pk.y = bfr(r0.z)|(bfr(r0.w)<<16);
            pk.z = bfr(r1.x)|(bfr(r1.y)<<16); pk.w = bfr(r1.z)|(bfr(r1.w)<<16);
            *(uint4*)&hb[(size_t)n*HD + c0] = pk;
        }
    }
}

// ===== edge-centric message kernel: one block per 64-slot chunk =====
// Single LDS buffer (21.5 KB -> 7 blocks/CU): m1/m2 overlay the feature tile
// after its reads complete. Gather chain is 1 coalesced + 1 random load.
__global__ __launch_bounds__(BLK, 7) void edge_msg_kernel(
    const u16* __restrict__ hb,
    const int* __restrict__ ssrc, const unsigned* __restrict__ sea,
    const int* __restrict__ sdst, const int* __restrict__ off,
    const float* __restrict__ rd,
    const u16* __restrict__ W1aT, const float* __restrict__ b1a,
    const u16* __restrict__ W1bT, const float* __restrict__ b1b,
    float* __restrict__ agg)
{
    __shared__ char bufA[TE*ASTR];   // [64][336B]: feat(k0..159) -> m1 -> m2

    const int tid = threadIdx.x;
    const int lane = tid & 63;
    const int l15 = lane & 15, lhi = lane >> 4;     // D: col=l15, row=lhi*4+reg
    const int w = tid >> 6;                          // wave -> c-tiles 2w,2w+1
    const int s0 = blockIdx.x * TE;                  // NE % 64 == 0: no tail
    const int cg = tid & 15, c0 = cg*8;
    const int myrow = tid >> 2, p = tid & 3;
    const int rowL = 16*w + l15;
    const int bl = lane >> 2;

    // issue early (consumed only after GEMMs; latency hidden under compute)
    const int d0 = sdst[s0];
    const int d1 = sdst[s0 + TE - 1];

    // zero k-tail [272,336): 4 x 16B per row (ea uint4 covers [256,272))
    for (int idx = tid; idx < TE*4; idx += BLK){
        const int r = idx >> 2, q = idx & 3;
        *(uint4*)(bufA + r*ASTR + 272 + q*16) = make_uint4(0u,0u,0u,0u);
    }

    // gather-stage hb[ssrc] rows + packed edge_attr
    {
        const int sv0 = ssrc[s0 + rowL];             // coalesced
        const int sv  = __shfl(sv0, bl);
        const uint4* sp = (const uint4*)(hb + (size_t)sv*HD);
        uint4* dp = (uint4*)(bufA + myrow*ASTR + p*64);
        #pragma unroll
        for (int q=0;q<4;++q) dp[q] = sp[p*4+q];
        if (p == 0){
            const unsigned eaw = sea[s0 + myrow];    // coalesced
            *(uint4*)(bufA + myrow*ASTR + 256) = make_uint4(eaw, 0u, 0u, 0u);
        }
    }
    __syncthreads();                               // BAR 1: tile staged

    // ---- GEMM1: m1[c][e] = W1a^T(160k) x feat ----
    f32x4 acc1[2][4];
    #pragma unroll
    for (int cc=0; cc<2; ++cc){
        const float4 bv = *(const float4*)&b1a[(2*w+cc)*16 + lhi*4];
        #pragma unroll
        for (int te=0; te<4; ++te){
            acc1[cc][te][0]=bv.x; acc1[cc][te][1]=bv.y;
            acc1[cc][te][2]=bv.z; acc1[cc][te][3]=bv.w;
        }
    }
    #pragma unroll
    for (int kk=0; kk<5; ++kk){
        const bf16x8 a0 = *(const bf16x8*)(W1aT + ((2*w  )*16 + l15)*160 + kk*32 + lhi*8);
        const bf16x8 a1 = *(const bf16x8*)(W1aT + ((2*w+1)*16 + l15)*160 + kk*32 + lhi*8);
        #pragma unroll
        for (int te=0; te<4; ++te){
            const bf16x8 bb = *(const bf16x8*)(bufA + (te*16+l15)*ASTR + kk*64 + lhi*16);
            acc1[0][te] = MFMA16(a0, bb, acc1[0][te], 0,0,0);
            acc1[1][te] = MFMA16(a1, bb, acc1[1][te], 0,0,0);
        }
    }
    __syncthreads();                               // BAR 2: all feat reads done
    #pragma unroll
    for (int cc=0; cc<2; ++cc){                    // m1 -> bufA rows [0,256)
        #pragma unroll
        for (int te=0; te<4; ++te){
            uint2 pk;
            pk.x = bfr(fmaxf(acc1[cc][te][0],0.f)) | (bfr(fmaxf(acc1[cc][te][1],0.f))<<16);
            pk.y = bfr(fmaxf(acc1[cc][te][2],0.f)) | (bfr(fmaxf(acc1[cc][te][3],0.f))<<16);
            *(uint2*)(bufA + (te*16+l15)*ASTR + (2*w+cc)*32 + lhi*8) = pk;
        }
    }
    __syncthreads();                               // BAR 3: m1 ready

    // ---- GEMM2: m2[c][e] = W1b^T(128k) x m1 ----
    f32x4 acc2[2][4];
    #pragma unroll
    for (int cc=0; cc<2; ++cc){
        const float4 bv = *(const float4*)&b1b[(2*w+cc)*16 + lhi*4];
        #pragma unroll
        for (int te=0; te<4; ++te){
            acc2[cc][te][0]=bv.x; acc2[cc][te][1]=bv.y;
            acc2[cc][te][2]=bv.z; acc2[cc][te][3]=bv.w;
        }
    }
    #pragma unroll
    for (int kk=0; kk<4; ++kk){
        const bf16x8 a0 = *(const bf16x8*)(W1bT + ((2*w  )*16 + l15)*128 + kk*32 + lhi*8);
        const bf16x8 a1 = *(const bf16x8*)(W1bT + ((2*w+1)*16 + l15)*128 + kk*32 + lhi*8);
        #pragma unroll
        for (int te=0; te<4; ++te){
            const bf16x8 bb = *(const bf16x8*)(bufA + (te*16+l15)*ASTR + kk*64 + lhi*16);
            acc2[0][te] = MFMA16(a0, bb, acc2[0][te], 0,0,0);
            acc2[1][te] = MFMA16(a1, bb, acc2[1][te], 0,0,0);
        }
    }
    __syncthreads();                               // BAR 4: m1 reads done
    #pragma unroll
    for (int cc=0; cc<2; ++cc){                    // m2 -> bufA rows [0,256)
        #pragma unroll
        for (int te=0; te<4; ++te){
            uint2 pk;
            pk.x = bfr(fmaxf(acc2[cc][te][0],0.f)) | (bfr(fmaxf(acc2[cc][te][1],0.f))<<16);
            pk.y = bfr(fmaxf(acc2[cc][te][2],0.f)) | (bfr(fmaxf(acc2[cc][te][3],0.f))<<16);
            *(uint2*)(bufA + (te*16+l15)*ASTR + (2*w+cc)*32 + lhi*8) = pk;
        }
    }
    __syncthreads();                               // BAR 5: m2 ready

    // ---- segmented reduce over dst-sorted slots ----
    const int ng = tid >> 4;
    for (int d = d0 + ng; d <= d1; d += 16){
        const int ob = off[d], oe = off[d+1];
        int lo = ob > s0 ? ob : s0;
        int hi = oe < s0 + TE ? oe : s0 + TE;
        if (lo >= hi) continue;                    // degree-0 gap node
        float s[8] = {0.f,0.f,0.f,0.f,0.f,0.f,0.f,0.f};
        for (int t = lo; t < hi; ++t){
            const uint4 v = *(const uint4*)(bufA + (t - s0)*ASTR + cg*16);
            s[0] += bf2f(v.x&0xffffu); s[1] += bf2f(v.x>>16);
            s[2] += bf2f(v.y&0xffffu); s[3] += bf2f(v.y>>16);
            s[4] += bf2f(v.z&0xffffu); s[5] += bf2f(v.z>>16);
            s[6] += bf2f(v.w&0xffffu); s[7] += bf2f(v.w>>16);
        }
        const float rdv = rd[d];
        #pragma unroll
        for (int j=0;j<8;++j) s[j] *= rdv;
        float* ap = &agg[(size_t)d*HD + c0];
        if (ob >= s0 && oe <= s0 + TE){            // interior: exclusive, direct store
            float4 a0 = make_float4(s[0],s[1],s[2],s[3]);
            float4 a1 = make_float4(s[4],s[5],s[6],s[7]);
            *(float4*)ap = a0; *(float4*)(ap+4) = a1;
        } else {                                   // boundary: atomic partial
            #pragma unroll
            for (int j=0;j<8;++j) atomAddF(ap+j, s[j]);
        }
    }
}

// ===== node update kernel: u = relu(W2a^T.[h;agg]); r = h + sigm(W2b^T.u) =====
__global__ __launch_bounds__(BLK, 4) void node_upd_kernel(
    const float* __restrict__ h, const u16* __restrict__ hb,
    const float* __restrict__ agg,
    const u16* __restrict__ W2aT, const float* __restrict__ b2a,
    const u16* __restrict__ W2bT, const float* __restrict__ b2b,
    float* __restrict__ rbuf)
{
    __shared__ char bufA[TE*ASTR];
    __shared__ char bufB[TE*BSTR];

    const int tid = threadIdx.x;
    const int lane = tid & 63;
    const int l15 = lane & 15, lhi = lane >> 4;
    const int w = tid >> 6;
    const int n0 = blockIdx.x * TE;
    const int myrow = tid >> 2, p = tid & 3;

    {   // stage hb rows n0..n0+63
        int n = n0 + myrow; if (n >= NN) n = NN-1;
        const uint4* sp = (const uint4*)(hb + (size_t)n*HD);
        uint4* dp = (uint4*)(bufA + myrow*ASTR + p*64);
        #pragma unroll
        for (int q=0;q<4;++q) dp[q] = sp[p*4+q];
    }
    __syncthreads();

    f32x4 accN[2][4];
    #pragma unroll
    for (int cc=0; cc<2; ++cc){
        const float4 bv = *(const float4*)&b2a[(2*w+cc)*16 + lhi*4];
        #pragma unroll
        for (int te=0; te<4; ++te){
            accN[cc][te][0]=bv.x; accN[cc][te][1]=bv.y;
            accN[cc][te][2]=bv.z; accN[cc][te][3]=bv.w;
        }
    }
    #pragma unroll
    for (int kk=0; kk<4; ++kk){                         // K-half 1: h
        const bf16x8 a0 = *(const bf16x8*)(W2aT + ((2*w  )*16 + l15)*256 + kk*32 + lhi*8);
        const bf16x8 a1 = *(const bf16x8*)(W2aT + ((2*w+1)*16 + l15)*256 + kk*32 + lhi*8);
        #pragma unroll
        for (int te=0; te<4; ++te){
            const bf16x8 bb = *(const bf16x8*)(bufA + (te*16+l15)*ASTR + kk*64 + lhi*16);
            accN[0][te] = MFMA16(a0, bb, accN[0][te], 0,0,0);
            accN[1][te] = MFMA16(a1, bb, accN[1][te], 0,0,0);
        }
    }
    __syncthreads();
    {   // stage agg rows (f32 -> bf16 pack); agg already mean-scaled
        int n = n0 + myrow; if (n >= NN) n = NN-1;
        const float4* sp = (const float4*)(agg + (size_t)n*HD + p*32);
        uint4* dp = (uint4*)(bufA + myrow*ASTR + p*64);
        #pragma unroll
        for (int q=0;q<4;++q){
            const float4 v0 = sp[q*2+0], v1 = sp[q*2+1];
            uint4 pk;
            pk.x = bfr(v0.x)|(bfr(v0.y)<<16); pk.y = bfr(v0.z)|(bfr(v0.w)<<16);
            pk.z = bfr(v1.x)|(bfr(v1.y)<<16); pk.w = bfr(v1.z)|(bfr(v1.w)<<16);
            dp[q] = pk;
        }
    }
    __syncthreads();
    #pragma unroll
    for (int kk=0; kk<4; ++kk){                         // K-half 2: agg
        const bf16x8 a0 = *(const bf16x8*)(W2aT + ((2*w  )*16 + l15)*256 + 128 + kk*32 + lhi*8);
        const bf16x8 a1 = *(const bf16x8*)(W2aT + ((2*w+1)*16 + l15)*256 + 128 + kk*32 + lhi*8);
        #pragma unroll
        for (int te=0; te<4; ++te){
            const bf16x8 bb = *(const bf16x8*)(bufA + (te*16+l15)*ASTR + kk*64 + lhi*16);
            accN[0][te] = MFMA16(a0, bb, accN[0][te], 0,0,0);
            accN[1][te] = MFMA16(a1, bb, accN[1][te], 0,0,0);
        }
    }
    #pragma unroll
    for (int cc=0; cc<2; ++cc){                         // u = relu -> bufB
        #pragma unroll
        for (int te=0; te<4; ++te){
            uint2 pk;
            pk.x = bfr(fmaxf(accN[cc][te][0],0.f)) | (bfr(fmaxf(accN[cc][te][1],0.f))<<16);
            pk.y = bfr(fmaxf(accN[cc][te][2],0.f)) | (bfr(fmaxf(accN[cc][te][3],0.f))<<16);
            *(uint2*)(bufB + (te*16+l15)*BSTR + (2*w+cc)*32 + lhi*8) = pk;
        }
    }
    __syncthreads();

    f32x4 accO[2][4];
    #pragma unroll
    for (int cc=0; cc<2; ++cc){
        const float4 bv = *(const float4*)&b2b[(2*w+cc)*16 + lhi*4];
        #pragma unroll
        for (int te=0; te<4; ++te){
            accO[cc][te][0]=bv.x; accO[cc][te][1]=bv.y;
            accO[cc][te][2]=bv.z; accO[cc][te][3]=bv.w;
        }
    }
    #pragma unroll
    for (int kk=0; kk<4; ++kk){
        const bf16x8 a0 = *(const bf16x8*)(W2bT + ((2*w  )*16 + l15)*128 + kk*32 + lhi*8);
        const bf16x8 a1 = *(const bf16x8*)(W2bT + ((2*w+1)*16 + l15)*128 + kk*32 + lhi*8);
        #pragma unroll
        for (int te=0; te<4; ++te){
            const bf16x8 bb = *(const bf16x8*)(bufB + (te*16+l15)*BSTR + kk*64 + lhi*16);
            accO[0][te] = MFMA16(a0, bb, accO[0][te], 0,0,0);
            accO[1][te] = MFMA16(a1, bb, accO[1][te], 0,0,0);
        }
    }
    #pragma unroll
    for (int cc=0; cc<2; ++cc){
        const int cbase = (2*w+cc)*16 + lhi*4;
        #pragma unroll
        for (int te=0; te<4; ++te){
            const int n = n0 + te*16 + l15;
            if (n < NN){
                const float4 hv = *(const float4*)&h[(size_t)n*HD + cbase];
                float4 r;
                r.x = hv.x + sigm(accO[cc][te][0]);
                r.y = hv.y + sigm(accO[cc][te][1]);
                r.z = hv.z + sigm(accO[cc][te][2]);
                r.w = hv.w + sigm(accO[cc][te][3]);
                *(float4*)&rbuf[(size_t)n*HD + cbase] = r;
            }
        }
    }
}

// ---------------- BN stats ----------------
__global__ void bn_stats_k(const float* __restrict__ r, float* __restrict__ bn){
    const int c = threadIdx.x & (HD-1);
    const int half = threadIdx.x >> 7;
    const int stride = gridDim.x * 2;
    float s = 0.f, ss = 0.f;
    for (int n = blockIdx.x*2 + half; n < NN; n += stride) {
        const float v = r[(size_t)n*HD + c];
        s += v; ss += v*v;
    }
    atomAddF(&bn[c], s);
    atomAddF(&bn[HD+c], ss);
}

// ---------------- BN normalize (writes f32 h + bf16 mirror) ----------------
__global__ void bn_norm_k(const float* __restrict__ r, const float* __restrict__ bn,
                          const float* __restrict__ gamma, const float* __restrict__ beta,
                          float* __restrict__ h, u16* __restrict__ hb){
    const int i = blockIdx.x*blockDim.x + threadIdx.x;  // float4 index
    const int n4 = NN*HD/4;
    if (i >= n4) return;
    const int c0 = (i*4) & (HD-1);
    float4 v = ((const float4*)r)[i];
    float* vp = (float*)&v;
    #pragma unroll
    for (int j=0;j<4;++j){
        const int c = c0 + j;
        const float mu  = bn[c] * (1.0f/NN);
        const float var = bn[HD+c] * (1.0f/NN) - mu*mu;
        const float sc  = rsqrtf(var + EPSV) * gamma[c];
        const float sh  = beta[c] - mu*sc;
        vp[j] = fmaf(vp[j], sc, sh);
    }
    ((float4*)h)[i] = v;
    uint2 pk;
    pk.x = bfr(vp[0]) | (bfr(vp[1])<<16);
    pk.y = bfr(vp[2]) | (bfr(vp[3])<<16);
    ((uint2*)hb)[i] = pk;
}

// ---------------- final MLP ----------------
__global__ __launch_bounds__(BLK) void final_kernel(
    const float* __restrict__ h,
    const float* __restrict__ Wf, const float* __restrict__ bf,
    const float* __restrict__ Wo, const float* __restrict__ bo,
    float* __restrict__ out)
{
    __shared__ float smem[130*SROW];
    __shared__ int s_src[TE];
    const int tid = threadIdx.x;
    const int n0 = blockIdx.x * TE;
    const int cg = tid & 15, eg = tid >> 4, c0 = cg*8;

    if (tid < TE) { int n = n0 + tid; s_src[tid] = (n < NN) ? n : NN-1; }
    __syncthreads();
    stage_rows(smem, h, s_src, tid);
    __syncthreads();

    float acc[4][8];
    #pragma unroll
    for (int j=0;j<8;++j){ float bv=bf[c0+j];
        #pragma unroll
        for (int i=0;i<4;++i) acc[i][j]=bv; }
    mv_acc(smem, HD, Wf, c0, eg, acc);
    __syncthreads();

    #pragma unroll
    for (int j=0;j<8;++j){
        float4 m0;
        m0.x=fmaxf(acc[0][j],0.f); m0.y=fmaxf(acc[1][j],0.f);
        m0.z=fmaxf(acc[2][j],0.f); m0.w=fmaxf(acc[3][j],0.f);
        *(float4*)&smem[(c0+j)*SROW + eg*4] = m0;
    }
    __syncthreads();

    const int e = tid >> 2, q = tid & 3;
    float s = 0.f;
    #pragma unroll
    for (int kk=0; kk<32; ++kk) {
        const int k = q*32 + kk;
        s = fmaf(smem[k*SROW + e], Wo[k], s);
    }
    s += __shfl_xor(s, 1);
    s += __shfl_xor(s, 2);
    const int n = n0 + e;
    if (q == 0 && n < NN)
        out[n] = sigm(s + bo[0]);
}

// ---------------- launch ----------------
extern "C" void kernel_launch(void* const* d_in, const int* in_sizes, int n_in,
                              void* d_out, int out_size, void* d_ws, size_t ws_size,
                              hipStream_t stream)
{
    const float* x    = (const float*)d_in[0];
    const float* ea   = (const float*)d_in[1];
    const int*   ei   = (const int*)d_in[2];
    const float* Win0 = (const float*)d_in[4];
    const float* bin0 = (const float*)d_in[5];
    const float* Win1 = (const float*)d_in[6];
    const float* bin1 = (const float*)d_in[7];
    const float* W1a  = (const float*)d_in[8];
    const float* b1a  = (const float*)d_in[9];
    const float* W1b  = (const float*)d_in[10];
    const float* b1b  = (const float*)d_in[11];
    const float* W2a  = (const float*)d_in[12];
    const float* b2a  = (const float*)d_in[13];
    const float* W2b  = (const float*)d_in[14];
    const float* b2b  = (const float*)d_in[15];
    const float* gmm  = (const float*)d_in[16];
    const float* bta  = (const float*)d_in[17];
    const float* Wf   = (const float*)d_in[18];
    const float* bfv  = (const float*)d_in[19];
    const float* Wo   = (const float*)d_in[20];
    const float* bo   = (const float*)d_in[21];
    float* out = (float*)d_out;

    char* p = (char*)d_ws;
    float* h     = (float*)p;  p += (size_t)NN*HD*4;
    float* rbuf  = (float*)p;  p += (size_t)NN*HD*4;
    float* agg   = (float*)p;  p += (size_t)NN*HD*4;
    u16*   hb    = (u16*)p;    p += (size_t)NN*HD*2;
    u16*   W1aT  = (u16*)p;    p += (size_t)3*128*160*2;
    u16*   W1bT  = (u16*)p;    p += (size_t)3*128*128*2;
    u16*   W2aT  = (u16*)p;    p += (size_t)3*128*256*2;
    u16*   W2bT  = (u16*)p;    p += (size_t)3*128*128*2;
    float* rd    = (float*)p;  p += (size_t)NN*4;
    float* bn    = (float*)p;  p += 256*4;
    int*   cnt   = (int*)p;    p += (size_t)NN*4;
    int*   fill  = (int*)p;    p += (size_t)NN*4;
    int*   off   = (int*)p;    p += (size_t)(NN+1)*4;
    int*   ssrc  = (int*)p;    p += (size_t)NE*4;
    int*   sdst  = (int*)p;    p += (size_t)NE*4;
    unsigned* sea = (unsigned*)p;

    const int* srcp = ei;
    const int* dstp = ei + NE;

    const int GN = (NN + TE - 1) / TE;     // 782
    const int GE = NE / TE;                // 12500
    const int G4 = (NN*HD/4 + 255) / 256;  // 6250

    // ---- CSR build ----
    zero_i_k<<<(2*NN+255)/256, 256, 0, stream>>>(cnt, 2*NN);
    count_k<<<(NE+255)/256, 256, 0, stream>>>(dstp, cnt);
    scan_k<<<1, 1024, 0, stream>>>(cnt, off);
    rdenom_k<<<(NN+255)/256, 256, 0, stream>>>(cnt, rd);
    fill_k<<<(NE+255)/256, 256, 0, stream>>>(srcp, dstp, ea, off, fill, ssrc, sea, sdst);

    // ---- weight convert/transpose to bf16 [c][k] ----
    wconv_k<<<dim3((128*160+255)/256,3), 256, 0, stream>>>(W1a, W1aT, 130, 160, 128);
    wconv_k<<<dim3((128*128+255)/256,3), 256, 0, stream>>>(W1b, W1bT, 128, 128, 128);
    wconv_k<<<dim3((128*256+255)/256,3), 256, 0, stream>>>(W2a, W2aT, 256, 256, 128);
    wconv_k<<<dim3((128*128+255)/256,3), 256, 0, stream>>>(W2b, W2bT, 128, 128, 128);

    input_mlp_k<<<GN, BLK, 0, stream>>>(x, Win0, bin0, Win1, bin1, h, hb);

    for (int l = 0; l < 3; ++l) {
        zero_agg_bn_k<<<G4, 256, 0, stream>>>((float4*)agg, NN*HD/4, bn);
        edge_msg_kernel<<<GE, BLK, 0, stream>>>(hb, ssrc, sea, sdst, off, rd,
            W1aT + (size_t)l*128*160, b1a + l*HD,
            W1bT + (size_t)l*128*128, b1b + l*HD, agg);
        node_upd_kernel<<<GN, BLK, 0, stream>>>(h, hb, agg,
            W2aT + (size_t)l*128*256, b2a + l*HD,
            W2bT + (size_t)l*128*128, b2b + l*HD, rbuf);
        bn_stats_k<<<400, 256, 0, stream>>>(rbuf, bn);
        bn_norm_k<<<G4, 256, 0, stream>>>(rbuf, bn, gmm + l*HD, bta + l*HD, h, hb);
    }

    final_kernel<<<GN, BLK, 0, stream>>>(h, Wf, bfv, Wo, bo, out);
}